// Round 17
// baseline (4992.799 us; speedup 1.0000x reference)
//
#include <hip/hip_runtime.h>
#include <cstdint>

#define NNODES 50000
#define NEDGES 800000
#define DIN 128
#define HID 256
#define NCLS 40
#define NBLK 3

// ---------------- CSR build: forward planar int32 (established) ---------------
__global__ void hist_kernel(const int* __restrict__ ei, int* __restrict__ cnt, int E) {
  int e = blockIdx.x * blockDim.x + threadIdx.x;
  if (e < E) atomicAdd(&cnt[ei[E + e]], 1);
}

__global__ void scan_kernel(const int* __restrict__ cnt, int* __restrict__ row_ptr, int N) {
  __shared__ int sums[1024];
  int t = threadIdx.x;
  int chunk = (N + 1023) >> 10;
  int beg = t * chunk;
  int end = beg + chunk; if (end > N) end = N;
  int s = 0;
  for (int i = beg; i < end; ++i) s += cnt[i];
  sums[t] = s;
  __syncthreads();
  for (int off = 1; off < 1024; off <<= 1) {
    int v = 0;
    if (t >= off) v = sums[t - off];
    __syncthreads();
    sums[t] += v;
    __syncthreads();
  }
  int run = (t == 0) ? 0 : sums[t - 1];
  for (int i = beg; i < end; ++i) {
    row_ptr[i] = run;
    run += cnt[i];
  }
  if (t == 1023) row_ptr[N] = run;
}

__global__ void fill_kernel(const int* __restrict__ ei,
                            const int* __restrict__ row_ptr, int* __restrict__ fillc,
                            int* __restrict__ col, int E) {
  int e = blockIdx.x * blockDim.x + threadIdx.x;
  if (e < E) {
    int s = ei[e];
    int d = ei[E + e];
    int pos = atomicAdd(&fillc[d], 1);
    col[row_ptr[d] + pos] = s;
  }
}

// ---------------- fp32 -> f64 param staging ----------------
__global__ __launch_bounds__(256)
void cvt_kernel(const float* __restrict__ src, double* __restrict__ dst, int n) {
  int i = blockIdx.x * 256 + threadIdx.x;
  if (i < n) dst[i] = (double)src[i];
}

// ---------------- mean aggregation: f64 accumulate, TS storage ---------------
template<typename TS>
__global__ __launch_bounds__(256)
void agg_kernel(const TS* __restrict__ x, TS* __restrict__ outf,
                const int* __restrict__ row_ptr, const int* __restrict__ col,
                const int* __restrict__ cnt) {
  const int wv   = threadIdx.x >> 6;
  const int lane = threadIdx.x & 63;
  const int n = blockIdx.x * 4 + wv;   // 12500*4 == 50000 exact
  int beg = row_ptr[n], end = row_ptr[n + 1];
  double s0 = 0, s1 = 0, s2 = 0, s3 = 0;
  for (int j = beg; j < end; ++j) {
    const TS* xr = x + (size_t)col[j] * HID + lane;
    s0 += (double)xr[0]; s1 += (double)xr[64]; s2 += (double)xr[128]; s3 += (double)xr[192];
  }
  int c = cnt[n];
  double cd = (double)(c > 0 ? c : 1);
  TS* o = outf + (size_t)n * HID + lane;
  o[0] = (TS)(s0 / cd); o[64] = (TS)(s1 / cd); o[128] = (TS)(s2 / cd); o[192] = (TS)(s3 / cd);
}

// ---------------- fold BN params (f64) ----------------
__global__ void fold_kernel(const double* __restrict__ b1l, const double* __restrict__ g1,
                            const double* __restrict__ bb1, const double* __restrict__ m1,
                            const double* __restrict__ v1,
                            const double* __restrict__ b2l, const double* __restrict__ g2,
                            const double* __restrict__ bb2, const double* __restrict__ m2,
                            const double* __restrict__ v2,
                            double* __restrict__ S1, double* __restrict__ T1,
                            double* __restrict__ S2, double* __restrict__ T2) {
  int idx = blockIdx.x * 256 + threadIdx.x;  // 0..767
  double s1 = g1[idx] / sqrt(v1[idx] + 1e-5);
  S1[idx] = s1;
  T1[idx] = (b1l[idx] - m1[idx]) * s1 + bb1[idx];
  double s2 = g2[idx] / sqrt(v2[idx] + 1e-5);
  S2[idx] = s2;
  T2[idx] = (b2l[idx] - m2[idx]) * s2 + bb2[idx];
}

// ---------------- tiled GEMM, f64 compute; A storage TA, C storage TS --------
// C[M,N] = epilogue(A1@B1 [+ A2@B2]); v = acc*S + Tv; optional relu.
template<typename TA, typename TS>
__global__ __launch_bounds__(256)
void gemm128(const TA* __restrict__ A1, const double* __restrict__ B1, int K1,
             const TS* __restrict__ A2, const double* __restrict__ B2, int K2,
             const double* __restrict__ S, const double* __restrict__ Tv,
             TS* __restrict__ C, int M, int N, int do_relu) {
  __shared__ double As[128][17];
  __shared__ double Bs[16][68];
  const int tid = threadIdx.x;
  const int tx = tid & 15;
  const int ty = tid >> 4;
  const int nT = N >> 6;
  const int m0 = (int)(blockIdx.x / nT) * 128;
  const int n0 = (int)(blockIdx.x % nT) * 64;
  double acc[8][4] = {};

  auto runA = [&](auto A, const double* B, int K) {
    for (int k0 = 0; k0 < K; k0 += 16) {
      __syncthreads();
#pragma unroll
      for (int e = 0; e < 8; e++) {
        int idx = tid + e * 256;
        int r = idx >> 4, kk = idx & 15;
        int row = m0 + r;
        As[r][kk] = (row < M) ? (double)A[(size_t)row * K + k0 + kk] : 0.0;
      }
#pragma unroll
      for (int e = 0; e < 4; e++) {
        int idx = tid + e * 256;
        int kk = idx >> 6, c = idx & 63;
        Bs[kk][c] = B[(size_t)(k0 + kk) * N + n0 + c];
      }
      __syncthreads();
#pragma unroll
      for (int kk = 0; kk < 16; ++kk) {
        double b0 = Bs[kk][tx * 4 + 0], b1 = Bs[kk][tx * 4 + 1];
        double b2 = Bs[kk][tx * 4 + 2], b3 = Bs[kk][tx * 4 + 3];
#pragma unroll
        for (int i = 0; i < 8; i++) {
          double a = As[ty * 8 + i][kk];
          acc[i][0] = fma(a, b0, acc[i][0]);
          acc[i][1] = fma(a, b1, acc[i][1]);
          acc[i][2] = fma(a, b2, acc[i][2]);
          acc[i][3] = fma(a, b3, acc[i][3]);
        }
      }
    }
  };

  runA(A1, B1, K1);
  if (A2) runA(A2, B2, K2);

#pragma unroll
  for (int i = 0; i < 8; i++) {
    int row = m0 + ty * 8 + i;
    if (row >= M) continue;
#pragma unroll
    for (int j = 0; j < 4; j++) {
      int cl = n0 + tx * 4 + j;
      double v = acc[i][j];
      if (S) v *= S[cl];
      v += Tv[cl];
      if (do_relu && v < 0.0) v = 0.0;
      C[(size_t)row * N + cl] = (TS)v;
    }
  }
}

// ---------------- cur-update GEMM: BM=32, BN=256, in-place safe ---------------
// Block owns rows [m0,m0+32): gate A-operand and resid reads stay in-rows.
template<typename TS, bool GATED>
__global__ __launch_bounds__(256)
void gemm_cur(const TS* __restrict__ A1, const double* __restrict__ B1,
              const TS* __restrict__ A2, const double* __restrict__ B2,
              const double* __restrict__ B3, const double* __restrict__ gb,
              const double* __restrict__ S, const double* __restrict__ Tv,
              const TS* __restrict__ resid, TS* __restrict__ C, int M) {
  __shared__ double As[32][17];
  __shared__ double Bs[16][260];
  const int tid = threadIdx.x;
  const int tx = tid & 31;
  const int ty = tid >> 5;
  const int m0 = (int)blockIdx.x * 32;
  double acc[4][8] = {};
  double accg[4][8] = {};

  auto run = [&](const TS* A, const double* B, double (&ac)[4][8]) {
    for (int k0 = 0; k0 < HID; k0 += 16) {
      __syncthreads();
#pragma unroll
      for (int e = 0; e < 2; e++) {
        int idx = tid + e * 256;
        int r = idx >> 4, kk = idx & 15;
        int row = m0 + r;
        As[r][kk] = (row < M) ? (double)A[(size_t)row * HID + k0 + kk] : 0.0;
      }
#pragma unroll
      for (int e = 0; e < 16; e++) {
        int idx = tid + e * 256;
        int kk = idx >> 8, c = idx & 255;
        Bs[kk][c] = B[(size_t)(k0 + kk) * HID + c];
      }
      __syncthreads();
#pragma unroll
      for (int kk = 0; kk < 16; ++kk) {
#pragma unroll
        for (int i = 0; i < 4; i++) {
          double a = As[ty * 4 + i][kk];
#pragma unroll
          for (int j = 0; j < 8; j++)
            ac[i][j] = fma(a, Bs[kk][tx * 8 + j], ac[i][j]);
        }
      }
    }
  };

  run(A1, B1, acc);
  run(A2, B2, acc);
  if constexpr (GATED) run(resid, B3, accg);

#pragma unroll
  for (int i = 0; i < 4; i++) {
    int row = m0 + ty * 4 + i;
    if (row >= M) continue;
#pragma unroll
    for (int j = 0; j < 8; j++) {
      int cl = tx * 8 + j;
      double v = acc[i][j] * S[cl] + Tv[cl];
      if (v < 0.0) v = 0.0;  // relu (always on this path)
      size_t base = (size_t)row * HID + cl;
      double p = (double)resid[base];
      if constexpr (GATED) {
        double g = 1.0 / (1.0 + exp(-(accg[i][j] + gb[cl])));
        v = g * p + (1.0 - g) * (v + p);
      } else {
        v += p;
      }
      C[base] = (TS)v;
    }
  }
}

// ---------------- classifier stage 2: [M,128]@[128,40] + b -> fp32 out --------
template<typename TS>
__global__ __launch_bounds__(256)
void classifier2(const TS* __restrict__ Tin, const double* __restrict__ W,
                 const double* __restrict__ bias, float* __restrict__ out, int M) {
  __shared__ double Ws[DIN * NCLS];
  __shared__ double bs[NCLS];
  int tid = threadIdx.x;
  for (int i = tid; i < DIN * NCLS; i += 256) Ws[i] = W[i];
  if (tid < NCLS) bs[tid] = bias[tid];
  __syncthreads();
  int row = blockIdx.x * 64 + (tid >> 2);
  int c0 = (tid & 3) * 10;
  if (row >= M) return;
  double s[10];
#pragma unroll
  for (int c = 0; c < 10; c++) s[c] = bs[c0 + c];
  const TS* tr = Tin + (size_t)row * DIN;
  for (int k = 0; k < DIN; k++) {
    double a = (double)tr[k];
#pragma unroll
    for (int c = 0; c < 10; c++) s[c] = fma(a, Ws[k * NCLS + c0 + c], s[c]);
  }
#pragma unroll
  for (int c = 0; c < 10; c++) out[(size_t)row * NCLS + c0 + c] = (float)s[c];
}

// ---------------- tier driver: TS = node-buffer storage type ------------------
template<typename TS>
static void launch_tier(void* const* d_in, float* out, char* base, hipStream_t stream,
                        const int* row_ptr, const int* col, const int* cnt) {
  const float* x = (const float*)d_in[0];
  size_t off = 0;
  auto alloc = [&](size_t bytes) -> void* {
    void* p = base + off;
    off += (bytes + 255) & ~(size_t)255;
    return p;
  };
  const size_t NODEB = (size_t)NNODES * HID * sizeof(TS);
  TS* P  = (TS*)alloc(NODEB);
  TS* AG = (TS*)alloc(NODEB);
  TS* H  = (TS*)alloc(NODEB);
  double* PRM = (double*)alloc((size_t)996776 * 8);
  double* S1 = (double*)alloc(768 * 8);
  double* T1 = (double*)alloc(768 * 8);
  double* S2 = (double*)alloc(768 * 8);
  double* T2 = (double*)alloc(768 * 8);

  static const int pn[22] = {32768, 256, 196608, 768, 196608, 196608, 768, 196608,
                             768, 768, 768, 768, 768, 768, 768, 768,
                             131072, 512, 32768, 128, 5120, 40};
  size_t poff[23];
  poff[0] = 0;
  for (int j = 0; j < 22; j++) poff[j + 1] = poff[j] + pn[j];
  for (int j = 0; j < 22; j++)
    cvt_kernel<<<(pn[j] + 255) / 256, 256, 0, stream>>>(
        (const float*)d_in[2 + j], PRM + poff[j], pn[j]);

  double* Wp_s   = PRM + poff[0];
  double* bp_s   = PRM + poff[1];
  double* W1l_s  = PRM + poff[2];
  double* b1l_s  = PRM + poff[3];
  double* W1r_s  = PRM + poff[4];
  double* W2l_s  = PRM + poff[5];
  double* b2l_s  = PRM + poff[6];
  double* W2r_s  = PRM + poff[7];
  double* bn1g_s = PRM + poff[8];
  double* bn1b_s = PRM + poff[9];
  double* bn1m_s = PRM + poff[10];
  double* bn1v_s = PRM + poff[11];
  double* bn2g_s = PRM + poff[12];
  double* bn2b_s = PRM + poff[13];
  double* bn2m_s = PRM + poff[14];
  double* bn2v_s = PRM + poff[15];
  double* gW_s   = PRM + poff[16];
  double* gb_s   = PRM + poff[17];
  double* Wc1_s  = PRM + poff[18];
  double* bc1_s  = PRM + poff[19];
  double* Wc2_s  = PRM + poff[20];
  double* bc2_s  = PRM + poff[21];

  fold_kernel<<<3, 256, 0, stream>>>(b1l_s, bn1g_s, bn1b_s, bn1m_s, bn1v_s,
                                     b2l_s, bn2g_s, bn2b_s, bn2m_s, bn2v_s,
                                     S1, T1, S2, T2);

  const int MT   = (NNODES + 127) / 128;  // 391
  const int g256 = MT * 4;
  const int g128 = MT * 2;
  const int gagg = NNODES / 4;            // 12500
  const int gcur = (NNODES + 31) / 32;    // 1563
  const int gcls = (NNODES + 63) / 64;    // 782

  // P = x @ Wp + bp  (A1 reads fp32 x directly)
  gemm128<float, TS><<<g256, 256, 0, stream>>>(
      x, Wp_s, DIN, (const TS*)nullptr, nullptr, 0, nullptr, bp_s, P, NNODES, HID, 0);

  for (int i = 0; i < NBLK; ++i) {
    const double* W1l_i = W1l_s + (size_t)i * HID * HID;
    const double* W1r_i = W1r_s + (size_t)i * HID * HID;
    const double* W2l_i = W2l_s + (size_t)i * HID * HID;
    const double* W2r_i = W2r_s + (size_t)i * HID * HID;
    // h1 = relu((agg(P)@W1l + P@W1r)*S1 + T1)
    agg_kernel<TS><<<gagg, 256, 0, stream>>>(P, AG, row_ptr, col, cnt);
    gemm128<TS, TS><<<g256, 256, 0, stream>>>(
        AG, W1l_i, HID, P, W1r_i, HID, S1 + i * HID, T1 + i * HID, H, NNODES, HID, 1);
    // cur = relu((agg(H)@W2l + H@W2r)*S2 + T2) [+P / gated] -> P in place
    agg_kernel<TS><<<gagg, 256, 0, stream>>>(H, AG, row_ptr, col, cnt);
    if (i == 0) {
      gemm_cur<TS, false><<<gcur, 256, 0, stream>>>(
          AG, W2l_i, H, W2r_i, nullptr, nullptr, S2, T2, P, P, NNODES);
    } else {
      gemm_cur<TS, true><<<gcur, 256, 0, stream>>>(
          AG, W2l_i, H, W2r_i, gW_s + (size_t)(i - 1) * HID * HID,
          gb_s + (size_t)(i - 1) * HID, S2 + i * HID, T2 + i * HID, P, P, NNODES);
    }
  }
  // H = relu(P @ Wc1 + bc1)  [N,128]
  gemm128<TS, TS><<<g128, 256, 0, stream>>>(
      P, Wc1_s, HID, (const TS*)nullptr, nullptr, 0, nullptr, bc1_s, H, NNODES, DIN, 1);
  classifier2<TS><<<gcls, 256, 0, stream>>>(H, Wc2_s, bc2_s, out, NNODES);
}

extern "C" void kernel_launch(void* const* d_in, const int* in_sizes, int n_in,
                              void* d_out, int out_size, void* d_ws, size_t ws_size,
                              hipStream_t stream) {
  const int* ei = (const int*)d_in[1];

  char* wsb = (char*)d_ws;
  size_t off = 0;
  auto alloc = [&](size_t bytes) -> void* {
    void* p = wsb + off;
    off += (bytes + 255) & ~(size_t)255;
    return p;
  };
  int* cnt     = (int*)alloc((size_t)NNODES * 4 * 2);
  int* fillc   = cnt + NNODES;
  int* row_ptr = (int*)alloc((size_t)(NNODES + 1) * 4);
  int* col     = (int*)alloc((size_t)NEDGES * 4);

  hipMemsetAsync(cnt, 0, (size_t)NNODES * 4 * 2, stream);
  int eb = (NEDGES + 255) / 256;
  hist_kernel<<<eb, 256, 0, stream>>>(ei, cnt, NEDGES);
  scan_kernel<<<1, 1024, 0, stream>>>(cnt, row_ptr, NNODES);
  fill_kernel<<<eb, 256, 0, stream>>>(ei, row_ptr, fillc, col, NEDGES);

  // f64 tier needs 3*102.4MB + 8MB params (+ this CSR prefix already counted in off)
  size_t need_f64 = 3ull * NNODES * HID * 8 + 996776ull * 8 + 4096 * 8 + (1 << 20);
  size_t remain = (ws_size > off) ? (ws_size - off) : 0;
  if (remain >= need_f64) {
    launch_tier<double>(d_in, (float*)d_out, wsb + off, stream, row_ptr, col, cnt);
  } else {
    launch_tier<float>(d_in, (float*)d_out, wsb + off, stream, row_ptr, col, cnt);
  }
}

// Round 18
// 4620.306 us; speedup vs baseline: 1.0806x; 1.0806x over previous
//
#include <hip/hip_runtime.h>
#include <cstdint>

#define NNODES 50000
#define NEDGES 800000
#define DIN 128
#define HID 256
#define NCLS 40
#define NBLK 3

// ---------------- CSR build: forward planar int32 (established) ---------------
__global__ void hist_kernel(const int* __restrict__ ei, int* __restrict__ cnt, int E) {
  int e = blockIdx.x * blockDim.x + threadIdx.x;
  if (e < E) atomicAdd(&cnt[ei[E + e]], 1);
}

__global__ void scan_kernel(const int* __restrict__ cnt, int* __restrict__ row_ptr, int N) {
  __shared__ int sums[1024];
  int t = threadIdx.x;
  int chunk = (N + 1023) >> 10;
  int beg = t * chunk;
  int end = beg + chunk; if (end > N) end = N;
  int s = 0;
  for (int i = beg; i < end; ++i) s += cnt[i];
  sums[t] = s;
  __syncthreads();
  for (int off = 1; off < 1024; off <<= 1) {
    int v = 0;
    if (t >= off) v = sums[t - off];
    __syncthreads();
    sums[t] += v;
    __syncthreads();
  }
  int run = (t == 0) ? 0 : sums[t - 1];
  for (int i = beg; i < end; ++i) {
    row_ptr[i] = run;
    run += cnt[i];
  }
  if (t == 1023) row_ptr[N] = run;
}

__global__ void fill_kernel(const int* __restrict__ ei,
                            const int* __restrict__ row_ptr, int* __restrict__ fillc,
                            int* __restrict__ col, int E) {
  int e = blockIdx.x * blockDim.x + threadIdx.x;
  if (e < E) {
    int s = ei[e];
    int d = ei[E + e];
    int pos = atomicAdd(&fillc[d], 1);
    col[row_ptr[d] + pos] = s;
  }
}

// ---------------- tiny f64 bias staging (bp, bc1) ----------------
__global__ void cvt_bias(const float* __restrict__ bp, const float* __restrict__ bc1,
                         double* __restrict__ bp64, double* __restrict__ bc164) {
  int i = threadIdx.x + blockIdx.x * 256;
  if (i < 256) bp64[i] = (double)bp[i];
  else if (i < 384) bc164[i - 256] = (double)bc1[i - 256];
}

// ---------------- fold BN params (fp32 in, f64 out) ----------------
__global__ void fold_kernel(const float* __restrict__ b1l, const float* __restrict__ g1,
                            const float* __restrict__ bb1, const float* __restrict__ m1,
                            const float* __restrict__ v1,
                            const float* __restrict__ b2l, const float* __restrict__ g2,
                            const float* __restrict__ bb2, const float* __restrict__ m2,
                            const float* __restrict__ v2,
                            double* __restrict__ S1, double* __restrict__ T1,
                            double* __restrict__ S2, double* __restrict__ T2) {
  int idx = blockIdx.x * 256 + threadIdx.x;  // 0..767
  double s1 = (double)g1[idx] / sqrt((double)v1[idx] + 1e-5);
  S1[idx] = s1;
  T1[idx] = ((double)b1l[idx] - (double)m1[idx]) * s1 + (double)bb1[idx];
  double s2 = (double)g2[idx] / sqrt((double)v2[idx] + 1e-5);
  S2[idx] = s2;
  T2[idx] = ((double)b2l[idx] - (double)m2[idx]) * s2 + (double)bb2[idx];
}

// ---------------- mean aggregation: fp32 storage, f64 accumulate --------------
__global__ __launch_bounds__(256)
void agg_kernel(const float* __restrict__ x, float* __restrict__ outf,
                const int* __restrict__ row_ptr, const int* __restrict__ col,
                const int* __restrict__ cnt) {
  const int wv   = threadIdx.x >> 6;
  const int lane = threadIdx.x & 63;
  const int n = blockIdx.x * 4 + wv;   // 12500*4 == 50000 exact
  int beg = row_ptr[n], end = row_ptr[n + 1];
  double s0 = 0, s1 = 0, s2 = 0, s3 = 0;
  for (int j = beg; j < end; ++j) {
    const float* xr = x + (size_t)col[j] * HID + lane;
    s0 += (double)xr[0]; s1 += (double)xr[64]; s2 += (double)xr[128]; s3 += (double)xr[192];
  }
  int c = cnt[n];
  double cd = (double)(c > 0 ? c : 1);
  float* o = outf + (size_t)n * HID + lane;
  o[0] = (float)(s0 / cd); o[64] = (float)(s1 / cd);
  o[128] = (float)(s2 / cd); o[192] = (float)(s3 / cd);
}

// ---------------- f64-compute GEMM, BM=128 BN=64 BK=16, fp32 storage ----------
// C[M,N] = epilogue(A1@B1 [+ A2@B2]); v = acc*S? + Tv; optional relu.
// Conflict-free mapping: thread (tx,ty) owns cols {j*16+tx}, rows {ty*8+i}.
template<bool TWOA>
__global__ __launch_bounds__(256)
void gemm_f64(const float* __restrict__ A1, const float* __restrict__ B1, int K1,
              const float* __restrict__ A2, const float* __restrict__ B2, int K2,
              const double* __restrict__ S, const double* __restrict__ Tv,
              float* __restrict__ C, int M, int N, int do_relu) {
  __shared__ double As[128][17];
  __shared__ double Bs[16][68];
  const int tid = threadIdx.x;
  const int tx = tid & 15;
  const int ty = tid >> 4;
  const int nT = N >> 6;
  const int m0 = (int)(blockIdx.x / nT) * 128;
  const int n0 = (int)(blockIdx.x % nT) * 64;
  double acc[8][4] = {};

  auto run = [&](const float* A, const float* B, int K) {
    for (int k0 = 0; k0 < K; k0 += 16) {
      __syncthreads();
#pragma unroll
      for (int e = 0; e < 8; e++) {
        int idx = tid + e * 256;
        int r = idx >> 4, kk = idx & 15;
        int row = m0 + r;
        As[r][kk] = (row < M) ? (double)A[(size_t)row * K + k0 + kk] : 0.0;
      }
#pragma unroll
      for (int e = 0; e < 4; e++) {
        int idx = tid + e * 256;
        int kk = idx >> 6, c = idx & 63;
        Bs[kk][c] = (double)B[(size_t)(k0 + kk) * N + n0 + c];
      }
      __syncthreads();
#pragma unroll
      for (int kk = 0; kk < 16; ++kk) {
        double b0 = Bs[kk][0 * 16 + tx], b1 = Bs[kk][1 * 16 + tx];
        double b2 = Bs[kk][2 * 16 + tx], b3 = Bs[kk][3 * 16 + tx];
#pragma unroll
        for (int i = 0; i < 8; i++) {
          double a = As[ty * 8 + i][kk];
          acc[i][0] = fma(a, b0, acc[i][0]);
          acc[i][1] = fma(a, b1, acc[i][1]);
          acc[i][2] = fma(a, b2, acc[i][2]);
          acc[i][3] = fma(a, b3, acc[i][3]);
        }
      }
    }
  };

  run(A1, B1, K1);
  if constexpr (TWOA) run(A2, B2, K2);

#pragma unroll
  for (int i = 0; i < 8; i++) {
    int row = m0 + ty * 8 + i;
    if (row >= M) continue;
#pragma unroll
    for (int j = 0; j < 4; j++) {
      int cl = n0 + j * 16 + tx;
      double v = acc[i][j];
      if (S) v *= S[cl];
      v += Tv[cl];
      if (do_relu && v < 0.0) v = 0.0;
      C[(size_t)row * N + cl] = (float)v;
    }
  }
}

// ---------------- cur-update GEMM: BM=64 BN=64, out-of-place ------------------
// cur = relu((AG@W2l + H@W2r)*S2+T2); GATED: z=P@B3+gb, g=sigmoid(z),
// cur = g*p + (1-g)*(cur+p); else cur += p.  C (=Z buffer) != P,AG,H.
template<bool GATED>
__global__ __launch_bounds__(256)
void gemm_cur64(const float* __restrict__ A1, const float* __restrict__ B1,
                const float* __restrict__ A2, const float* __restrict__ B2,
                const float* __restrict__ B3, const float* __restrict__ gb,
                const double* __restrict__ S, const double* __restrict__ Tv,
                const float* __restrict__ P, float* __restrict__ C, int M) {
  __shared__ double As[64][17];
  __shared__ double Bs[16][68];
  const int tid = threadIdx.x;
  const int tx = tid & 15;
  const int ty = tid >> 4;
  const int m0 = (int)(blockIdx.x >> 2) * 64;
  const int n0 = (int)(blockIdx.x & 3) * 64;
  double acc[4][4] = {};
  double accg[4][4] = {};

  auto run = [&](const float* A, const float* B, double (&ac)[4][4]) {
    for (int k0 = 0; k0 < HID; k0 += 16) {
      __syncthreads();
#pragma unroll
      for (int e = 0; e < 4; e++) {
        int idx = tid + e * 256;
        int r = idx >> 4, kk = idx & 15;
        int row = m0 + r;
        As[r][kk] = (row < M) ? (double)A[(size_t)row * HID + k0 + kk] : 0.0;
      }
#pragma unroll
      for (int e = 0; e < 4; e++) {
        int idx = tid + e * 256;
        int kk = idx >> 6, c = idx & 63;
        Bs[kk][c] = (double)B[(size_t)(k0 + kk) * HID + n0 + c];
      }
      __syncthreads();
#pragma unroll
      for (int kk = 0; kk < 16; ++kk) {
        double b0 = Bs[kk][0 * 16 + tx], b1 = Bs[kk][1 * 16 + tx];
        double b2 = Bs[kk][2 * 16 + tx], b3 = Bs[kk][3 * 16 + tx];
#pragma unroll
        for (int i = 0; i < 4; i++) {
          double a = As[ty * 4 + i][kk];
          ac[i][0] = fma(a, b0, ac[i][0]);
          ac[i][1] = fma(a, b1, ac[i][1]);
          ac[i][2] = fma(a, b2, ac[i][2]);
          ac[i][3] = fma(a, b3, ac[i][3]);
        }
      }
    }
  };

  run(A1, B1, acc);
  run(A2, B2, acc);
  if constexpr (GATED) run(P, B3, accg);

#pragma unroll
  for (int i = 0; i < 4; i++) {
    int row = m0 + ty * 4 + i;
    if (row >= M) continue;
#pragma unroll
    for (int j = 0; j < 4; j++) {
      int cl = n0 + j * 16 + tx;
      double v = acc[i][j] * S[cl] + Tv[cl];
      if (v < 0.0) v = 0.0;  // relu (always on this path)
      size_t base = (size_t)row * HID + cl;
      double p = (double)P[base];
      if constexpr (GATED) {
        double g = 1.0 / (1.0 + exp(-(accg[i][j] + (double)gb[cl])));
        v = g * p + (1.0 - g) * (v + p);
      } else {
        v += p;
      }
      C[base] = (float)v;
    }
  }
}

// ---------------- classifier stage 2: [M,128]@[128,40] + b -> fp32 out --------
__global__ __launch_bounds__(256)
void classifier2(const float* __restrict__ Tin, const float* __restrict__ W,
                 const float* __restrict__ bias, float* __restrict__ out, int M) {
  __shared__ double Ws[DIN * NCLS];
  __shared__ double bs[NCLS];
  int tid = threadIdx.x;
  for (int i = tid; i < DIN * NCLS; i += 256) Ws[i] = (double)W[i];
  if (tid < NCLS) bs[tid] = (double)bias[tid];
  __syncthreads();
  int row = blockIdx.x * 64 + (tid >> 2);
  int c0 = (tid & 3) * 10;
  if (row >= M) return;
  double s[10];
#pragma unroll
  for (int c = 0; c < 10; c++) s[c] = bs[c0 + c];
  const float* tr = Tin + (size_t)row * DIN;
  for (int k = 0; k < DIN; k++) {
    double a = (double)tr[k];
#pragma unroll
    for (int c = 0; c < 10; c++) s[c] = fma(a, Ws[k * NCLS + c0 + c], s[c]);
  }
#pragma unroll
  for (int c = 0; c < 10; c++) out[(size_t)row * NCLS + c0 + c] = (float)s[c];
}

extern "C" void kernel_launch(void* const* d_in, const int* in_sizes, int n_in,
                              void* d_out, int out_size, void* d_ws, size_t ws_size,
                              hipStream_t stream) {
  const float* x      = (const float*)d_in[0];
  const int*   ei     = (const int*)d_in[1];
  const float* Wp     = (const float*)d_in[2];
  const float* bp     = (const float*)d_in[3];
  const float* W1l    = (const float*)d_in[4];
  const float* b1l    = (const float*)d_in[5];
  const float* W1r    = (const float*)d_in[6];
  const float* W2l    = (const float*)d_in[7];
  const float* b2l    = (const float*)d_in[8];
  const float* W2r    = (const float*)d_in[9];
  const float* bn1_g  = (const float*)d_in[10];
  const float* bn1_b  = (const float*)d_in[11];
  const float* bn1_m  = (const float*)d_in[12];
  const float* bn1_v  = (const float*)d_in[13];
  const float* bn2_g  = (const float*)d_in[14];
  const float* bn2_b  = (const float*)d_in[15];
  const float* bn2_m  = (const float*)d_in[16];
  const float* bn2_v  = (const float*)d_in[17];
  const float* gate_W = (const float*)d_in[18];
  const float* gate_b = (const float*)d_in[19];
  const float* Wc1    = (const float*)d_in[20];
  const float* bc1    = (const float*)d_in[21];
  const float* Wc2    = (const float*)d_in[22];
  const float* bc2    = (const float*)d_in[23];

  char* wsb = (char*)d_ws;
  size_t off = 0;
  auto alloc = [&](size_t bytes) -> void* {
    void* p = wsb + off;
    off += (bytes + 255) & ~(size_t)255;
    return p;
  };
  const size_t NODEB = (size_t)NNODES * HID * 4;  // 51.2 MB
  float* P  = (float*)alloc(NODEB);
  float* AG = (float*)alloc(NODEB);
  float* H  = (float*)alloc(NODEB);
  float* Z  = (float*)alloc(NODEB);
  int* cnt     = (int*)alloc((size_t)NNODES * 4 * 2);
  int* fillc   = cnt + NNODES;
  int* row_ptr = (int*)alloc((size_t)(NNODES + 1) * 4);
  int* col     = (int*)alloc((size_t)NEDGES * 4);
  double* S1 = (double*)alloc(NBLK * HID * 8);
  double* T1 = (double*)alloc(NBLK * HID * 8);
  double* S2 = (double*)alloc(NBLK * HID * 8);
  double* T2 = (double*)alloc(NBLK * HID * 8);
  double* bp64  = (double*)alloc(HID * 8);
  double* bc164 = (double*)alloc(DIN * 8);

  hipMemsetAsync(cnt, 0, (size_t)NNODES * 4 * 2, stream);
  int eb = (NEDGES + 255) / 256;
  hist_kernel<<<eb, 256, 0, stream>>>(ei, cnt, NEDGES);
  scan_kernel<<<1, 1024, 0, stream>>>(cnt, row_ptr, NNODES);
  fill_kernel<<<eb, 256, 0, stream>>>(ei, row_ptr, fillc, col, NEDGES);
  cvt_bias<<<2, 256, 0, stream>>>(bp, bc1, bp64, bc164);
  fold_kernel<<<3, 256, 0, stream>>>(b1l, bn1_g, bn1_b, bn1_m, bn1_v,
                                     b2l, bn2_g, bn2_b, bn2_m, bn2_v, S1, T1, S2, T2);

  const int MT   = (NNODES + 127) / 128;   // 391
  const int g256 = MT * 4;                 // N=256 tiles
  const int g128t = MT * 2;                // N=128 tiles
  const int gagg = NNODES / 4;             // 12500
  const int gcur = ((NNODES + 63) / 64) * 4;  // 782*4 = 3128
  const int gcls = (NNODES + 63) / 64;     // 782

  // P = x @ Wp + bp
  gemm_f64<false><<<g256, 256, 0, stream>>>(
      x, Wp, DIN, nullptr, nullptr, 0, nullptr, bp64, P, NNODES, HID, 0);

  for (int i = 0; i < NBLK; ++i) {
    const float* W1l_i = W1l + (size_t)i * HID * HID;
    const float* W1r_i = W1r + (size_t)i * HID * HID;
    const float* W2l_i = W2l + (size_t)i * HID * HID;
    const float* W2r_i = W2r + (size_t)i * HID * HID;
    // h1 = relu((agg(P)@W1l + P@W1r)*S1 + T1)
    agg_kernel<<<gagg, 256, 0, stream>>>(P, AG, row_ptr, col, cnt);
    gemm_f64<true><<<g256, 256, 0, stream>>>(
        AG, W1l_i, HID, P, W1r_i, HID, S1 + i * HID, T1 + i * HID, H, NNODES, HID, 1);
    // cur = relu((agg(H)@W2l + H@W2r)*S2 + T2) [+P / gated] -> Z (out of place)
    agg_kernel<<<gagg, 256, 0, stream>>>(H, AG, row_ptr, col, cnt);
    if (i == 0) {
      gemm_cur64<false><<<gcur, 256, 0, stream>>>(
          AG, W2l_i, H, W2r_i, nullptr, nullptr, S2, T2, P, Z, NNODES);
    } else {
      gemm_cur64<true><<<gcur, 256, 0, stream>>>(
          AG, W2l_i, H, W2r_i, gate_W + (size_t)(i - 1) * HID * HID,
          gate_b + (size_t)(i - 1) * HID, S2 + i * HID, T2 + i * HID, P, Z, NNODES);
    }
    float* tmp = P; P = Z; Z = tmp;  // rotate: new prev = cur
  }
  // AG = relu(P @ Wc1 + bc1)  [N,128]
  gemm_f64<false><<<g128t, 256, 0, stream>>>(
      P, Wc1, HID, nullptr, nullptr, 0, nullptr, bc164, AG, NNODES, DIN, 1);
  classifier2<<<gcls, 256, 0, stream>>>(AG, Wc2, bc2, (float*)d_out, NNODES);
}